// Round 5
// baseline (18.237 us; speedup 1.0000x reference)
//
#include <hip/hip_runtime.h>

// Problem constants (fixed by setup_inputs: N=4096, box=50, cutoff=5)
#define N_ATOMS 4096
#define CUTOFF_SQ 25.0f

typedef float f4 __attribute__((ext_vector_type(4)));

// R3 layout (proven best): 8-row x 4-col block per thread, dense float4
// stores (consecutive lanes -> consecutive 16B => 1KB dense wave stores).
// R4 change: NONTEMPORAL stores (nt) to bypass L2 write-allocate -- the
// output is write-once/never-read, and 64MiB through a 32MiB L2 thrashes.
// Also: d2!=0 check dropped (provably redundant: d2==0 -> both write +0.0),
// and the j>=i predicate only computed in the diagonal band (j0 < i0+8).
__global__ __launch_bounds__(256) void pairdist_kernel(
    const float* __restrict__ q,      // [N,3] positions
    const float* __restrict__ cell,   // [3] box lengths
    float* __restrict__ out)          // [N,N] output
{
    const int rowgrp = blockIdx.x >> 2;                      // 0..511
    const int i0 = rowgrp << 3;                              // 8 rows, uniform
    const int colt = ((blockIdx.x & 3) << 8) + threadIdx.x;  // 0..1023
    const int j0 = colt << 2;                                // first col

    float* outp = out + (size_t)i0 * N_ATOMS + j0;

    // Entirely below the diagonal for all 8 rows -> dense zero streaming.
    if (j0 + 4 <= i0) {
        const f4 z = {0.f, 0.f, 0.f, 0.f};
#pragma unroll
        for (int r = 0; r < 8; ++r)
            __builtin_nontemporal_store(z,
                reinterpret_cast<f4*>(outp + (size_t)r * N_ATOMS));
        return;
    }

    const float cx = cell[0], cy = cell[1], cz = cell[2];

    // Row positions (block-uniform address -> scalar loads)
    const float* qi = q + 3 * i0;
    float xi[8], yi[8], zi[8];
#pragma unroll
    for (int r = 0; r < 8; ++r) {
        xi[r] = qi[3 * r + 0];
        yi[r] = qi[3 * r + 1];
        zi[r] = qi[3 * r + 2];
    }

    // Column positions: 4 atoms x 12B = 48B = 3 x float4, 16B-aligned.
    union { f4 v[3]; float s[12]; } u;
    const f4* q4 = reinterpret_cast<const f4*>(q);
#pragma unroll
    for (int m = 0; m < 3; ++m) u.v[m] = q4[3 * colt + m];

    if (j0 >= i0 + 8) {
        // Strictly above the diagonal for all 8 rows: no triu predicate.
#pragma unroll
        for (int r = 0; r < 8; ++r) {
            const float xr = xi[r], yr = yi[r], zr = zi[r];
            float res[4];
#pragma unroll
            for (int k = 0; k < 4; ++k) {
                float dx = fabsf(u.s[3 * k + 0] - xr); dx = fminf(dx, cx - dx);
                float dy = fabsf(u.s[3 * k + 1] - yr); dy = fminf(dy, cy - dy);
                float dz = fabsf(u.s[3 * k + 2] - zr); dz = fminf(dz, cz - dz);
                const float d2 = fmaf(dz, dz, fmaf(dy, dy, dx * dx));
                res[k] = (d2 < CUTOFF_SQ) ? d2 : 0.0f;
            }
            f4 v = {res[0], res[1], res[2], res[3]};
            __builtin_nontemporal_store(v,
                reinterpret_cast<f4*>(outp + (size_t)r * N_ATOMS));
        }
    } else {
        // Diagonal band (~0.3% of threads): full triu predicate.
#pragma unroll
        for (int r = 0; r < 8; ++r) {
            const float xr = xi[r], yr = yi[r], zr = zi[r];
            const int ir = i0 + r;
            float res[4];
#pragma unroll
            for (int k = 0; k < 4; ++k) {
                float dx = fabsf(u.s[3 * k + 0] - xr); dx = fminf(dx, cx - dx);
                float dy = fabsf(u.s[3 * k + 1] - yr); dy = fminf(dy, cy - dy);
                float dz = fabsf(u.s[3 * k + 2] - zr); dz = fminf(dz, cz - dz);
                const float d2 = fmaf(dz, dz, fmaf(dy, dy, dx * dx));
                const bool keep = (d2 < CUTOFF_SQ) & ((j0 + k) >= ir);
                res[k] = keep ? d2 : 0.0f;
            }
            f4 v = {res[0], res[1], res[2], res[3]};
            __builtin_nontemporal_store(v,
                reinterpret_cast<f4*>(outp + (size_t)r * N_ATOMS));
        }
    }
}

extern "C" void kernel_launch(void* const* d_in, const int* in_sizes, int n_in,
                              void* d_out, int out_size, void* d_ws, size_t ws_size,
                              hipStream_t stream) {
    const float* q    = (const float*)d_in[0];
    const float* cell = (const float*)d_in[1];
    float* out = (float*)d_out;

    // 512 rowgrps (8 rows each) x 4 col-segment blocks
    const int grid = 2048;
    pairdist_kernel<<<grid, 256, 0, stream>>>(q, cell, out);
}

// Round 6
// 16.338 us; speedup vs baseline: 1.1162x; 1.1162x over previous
//
#include <hip/hip_runtime.h>

// Problem constants (fixed by setup_inputs: N=4096, box=50, cutoff=5)
#define N_ATOMS 4096
#define CUTOFF_SQ 25.0f

typedef float f4 __attribute__((ext_vector_type(4)));

// Fill-like store stream: one block = 4 FULL rows = one contiguous 64KB
// output region. 1024 threads; thread t owns cols [4t..4t+3] of each of the
// 4 rows -> one dense float4 store per row, and the block's 16 waves cover
// each 16KB row span densely, rows consecutive => block writes 64KB
// sequentially. 1024 blocks = 2 resident rounds/CU (queued blocks rebalance
// the zero-block / compute-block imbalance).
// Regular stores (R4 proved nt hurts). d2!=0 dropped (provably redundant).
__global__ __launch_bounds__(1024) void pairdist_kernel(
    const float* __restrict__ q,      // [N,3] positions
    const float* __restrict__ cell,   // [3] box lengths
    float* __restrict__ out)          // [N,N] output
{
    const int i0 = blockIdx.x << 2;          // 4 rows, block-uniform
    const int t  = threadIdx.x;              // 0..1023
    const int j0 = t << 2;                   // first col

    float* outp = out + (size_t)i0 * N_ATOMS + j0;

    // Thread fully below the diagonal for all 4 rows -> dense zero stores.
    if (j0 + 4 <= i0) {
        const f4 z = {0.f, 0.f, 0.f, 0.f};
#pragma unroll
        for (int r = 0; r < 4; ++r)
            *reinterpret_cast<f4*>(outp + (size_t)r * N_ATOMS) = z;
        return;
    }

    const float cx = cell[0], cy = cell[1], cz = cell[2];

    // Row positions (block-uniform address -> scalar loads)
    const float* qi = q + 3 * i0;
    float xi[4], yi[4], zi[4];
#pragma unroll
    for (int r = 0; r < 4; ++r) {
        xi[r] = qi[3 * r + 0];
        yi[r] = qi[3 * r + 1];
        zi[r] = qi[3 * r + 2];
    }

    // Column positions: 4 atoms x 12B = 48B = 3 x float4, 16B-aligned.
    union { f4 v[3]; float s[12]; } u;
    const f4* q4 = reinterpret_cast<const f4*>(q);
#pragma unroll
    for (int m = 0; m < 3; ++m) u.v[m] = q4[3 * t + m];

    if (j0 >= i0 + 4) {
        // Strictly above the diagonal for all 4 rows: no triu predicate.
#pragma unroll
        for (int r = 0; r < 4; ++r) {
            const float xr = xi[r], yr = yi[r], zr = zi[r];
            float res[4];
#pragma unroll
            for (int k = 0; k < 4; ++k) {
                float dx = fabsf(u.s[3 * k + 0] - xr); dx = fminf(dx, cx - dx);
                float dy = fabsf(u.s[3 * k + 1] - yr); dy = fminf(dy, cy - dy);
                float dz = fabsf(u.s[3 * k + 2] - zr); dz = fminf(dz, cz - dz);
                const float d2 = fmaf(dz, dz, fmaf(dy, dy, dx * dx));
                res[k] = (d2 < CUTOFF_SQ) ? d2 : 0.0f;
            }
            f4 v = {res[0], res[1], res[2], res[3]};
            *reinterpret_cast<f4*>(outp + (size_t)r * N_ATOMS) = v;
        }
    } else {
        // Diagonal tile (exactly one thread per block: j0 == i0).
#pragma unroll
        for (int r = 0; r < 4; ++r) {
            const float xr = xi[r], yr = yi[r], zr = zi[r];
            const int ir = i0 + r;
            float res[4];
#pragma unroll
            for (int k = 0; k < 4; ++k) {
                float dx = fabsf(u.s[3 * k + 0] - xr); dx = fminf(dx, cx - dx);
                float dy = fabsf(u.s[3 * k + 1] - yr); dy = fminf(dy, cy - dy);
                float dz = fabsf(u.s[3 * k + 2] - zr); dz = fminf(dz, cz - dz);
                const float d2 = fmaf(dz, dz, fmaf(dy, dy, dx * dx));
                const bool keep = (d2 < CUTOFF_SQ) & ((j0 + k) >= ir);
                res[k] = keep ? d2 : 0.0f;
            }
            f4 v = {res[0], res[1], res[2], res[3]};
            *reinterpret_cast<f4*>(outp + (size_t)r * N_ATOMS) = v;
        }
    }
}

extern "C" void kernel_launch(void* const* d_in, const int* in_sizes, int n_in,
                              void* d_out, int out_size, void* d_ws, size_t ws_size,
                              hipStream_t stream) {
    const float* q    = (const float*)d_in[0];
    const float* cell = (const float*)d_in[1];
    float* out = (float*)d_out;

    // 1024 blocks x 4 rows each = 4096 rows; 1024 threads cover 4096 cols.
    pairdist_kernel<<<1024, 1024, 0, stream>>>(q, cell, out);
}